// Round 15
// baseline (137.667 us; speedup 1.0000x reference)
//
#include <hip/hip_runtime.h>
#include <hip/hip_bf16.h>

#define D_DIM 4096
#define N_TOK 4096
#define K_EXP 64
#define R_RANK 16
#define KR 1024               // K_EXP * R_RANK
#define SCALE_F 2.0f          // ALPHA / RANK
#define SPLIT_S 16
#define KC_S (D_DIM / SPLIT_S)   // 256
#define SPLIT_G 4
#define KC_G (D_DIM / SPLIT_G)   // 1024

typedef __attribute__((ext_vector_type(8))) short short8_t;   // 8 x bf16
typedef __attribute__((ext_vector_type(4))) float f32x4_t;
typedef __attribute__((ext_vector_type(4))) unsigned short u16x4_t;

__device__ __forceinline__ unsigned short f2bf(float f) {
  unsigned int u = __builtin_bit_cast(unsigned int, f);
  u += 0x7fffu + ((u >> 16) & 1u);          // RTNE
  return (unsigned short)(u >> 16);
}
__device__ __forceinline__ float bf2f(unsigned short h) {
  return __builtin_bit_cast(float, ((unsigned int)h) << 16);
}

// hi/lo split of 8 f32 -> bf16 hi + bf16 lo
__device__ __forceinline__ void cvt_hilo8(const f32x4_t a, const f32x4_t b,
                                          short8_t& h, short8_t& l) {
#pragma unroll
  for (int j = 0; j < 8; ++j) {
    float f = (j < 4) ? a[j & 3] : b[j & 3];
    __hip_bfloat16 hb = __float2bfloat16(f);
    float hf = __bfloat162float(hb);
    __hip_bfloat16 lb = __float2bfloat16(f - hf);
    h[j] = (short)__builtin_bit_cast(unsigned short, hb);
    l[j] = (short)__builtin_bit_cast(unsigned short, lb);
  }
}

// async global->LDS, 16B per lane. LDS dest must be wave-uniform base + lane*16.
__device__ __forceinline__ void gload16(const void* g, void* l) {
  __builtin_amdgcn_global_load_lds(
      (const __attribute__((address_space(1))) unsigned int*)g,
      (__attribute__((address_space(3))) unsigned int*)l, 16, 0, 0);
}

#define BARR() __builtin_amdgcn_s_barrier()
#define FENCE() __builtin_amdgcn_sched_barrier(0)
#define WAIT_LGKM0() asm volatile("s_waitcnt lgkmcnt(0)" ::: "memory")
#define WAIT_VM(n) asm volatile("s_waitcnt vmcnt(" #n ")" ::: "memory")

// ---------------- Wr (64,4096) f32 -> Wrh, Wrl bf16 (hi/lo split) ----------------
__global__ __launch_bounds__(512)
void pack_wr(const float* __restrict__ Wr,
             unsigned short* __restrict__ Wrh, unsigned short* __restrict__ Wrl) {
  int i = blockIdx.x * 512 + threadIdx.x;          // 65536 quads
  f32x4_t v = *(const f32x4_t*)(Wr + (size_t)i * 4);
  u16x4_t h, l;
#pragma unroll
  for (int j = 0; j < 4; ++j) {
    __hip_bfloat16 hb = __float2bfloat16(v[j]);
    float hf = __bfloat162float(hb);
    __hip_bfloat16 lb = __float2bfloat16(v[j] - hf);
    h[j] = __builtin_bit_cast(unsigned short, hb);
    l[j] = __builtin_bit_cast(unsigned short, lb);
  }
  *(u16x4_t*)(Wrh + (size_t)i * 4) = h;
  *(u16x4_t*)(Wrl + (size_t)i * 4) = l;
}

// ---------------- fused front-end: scores (0..511) | pack A (512..1023) | pack B (1024..1151)
union FatSmem {
  struct {
    unsigned short Ah[128 * 64];
    unsigned short Al[128 * 64];
    unsigned short Wh[2][64 * 64];
    unsigned short Wl[2][64 * 64];
  } sc;                                   // 64 KB (scores)
  unsigned short T[16][1032];             // 33 KB (pack B transpose)
};

__global__ __launch_bounds__(512, 4)
void fused_front(const float* __restrict__ x,
                 const unsigned short* __restrict__ Wrh,
                 const unsigned short* __restrict__ Wrl,
                 float* __restrict__ P, unsigned short* __restrict__ Xb,
                 const float* __restrict__ A, unsigned short* __restrict__ Ab,
                 const float* __restrict__ B, unsigned short* __restrict__ Wb) {
  __shared__ FatSmem sm;
  const int blk = blockIdx.x;
  const int t = threadIdx.x;

  if (blk >= 1024) {
    // ---------- pack B (K,D,R) f32 -> Wb (D, K*16+r) bf16, LDS transpose ----------
    int d0 = (blk - 1024) * 32;
#pragma unroll
    for (int half = 0; half < 2; ++half) {
      int dh = d0 + half * 16;
      if (half) __syncthreads();
#pragma unroll
      for (int it = 0; it < 2; ++it) {
        int s = it * 512 + t;              // 0..1023
        int k = s >> 4, d = s & 15;
        const float* src = B + ((size_t)k * D_DIM + dh + d) * R_RANK;
        f32x4_t v0 = *(const f32x4_t*)src;
        f32x4_t v1 = *(const f32x4_t*)(src + 4);
        f32x4_t v2 = *(const f32x4_t*)(src + 8);
        f32x4_t v3 = *(const f32x4_t*)(src + 12);
        u16x4_t o0, o1, o2, o3;
#pragma unroll
        for (int j = 0; j < 4; ++j) {
          o0[j] = f2bf(v0[j]); o1[j] = f2bf(v1[j]);
          o2[j] = f2bf(v2[j]); o3[j] = f2bf(v3[j]);
        }
        *(u16x4_t*)(&sm.T[d][k * 16 + 0])  = o0;
        *(u16x4_t*)(&sm.T[d][k * 16 + 4])  = o1;
        *(u16x4_t*)(&sm.T[d][k * 16 + 8])  = o2;
        *(u16x4_t*)(&sm.T[d][k * 16 + 12]) = o3;
      }
      __syncthreads();
#pragma unroll
      for (int it = 0; it < 4; ++it) {
        int idx = it * 512 + t;            // 0..2047
        int d = idx >> 7, off = (idx & 127) * 8;
        short8_t v = *(const short8_t*)(&sm.T[d][off]);
        *(short8_t*)(Wb + (size_t)(dh + d) * KR + off) = v;
      }
    }
    return;
  }
  if (blk >= 512) {
    // ---------- pack A (KR x D) f32 -> bf16, grid-stride ----------
    for (int i = (blk - 512) * 512 + t; i < KR * D_DIM / 4; i += 512 * 512) {
      f32x4_t v = *(const f32x4_t*)(A + (size_t)i * 4);
      u16x4_t o;
      o[0] = f2bf(v[0]); o[1] = f2bf(v[1]); o[2] = f2bf(v[2]); o[3] = f2bf(v[3]);
      *(u16x4_t*)(Ab + (size_t)i * 4) = o;
    }
    return;
  }

  // ---------- scores v6 (R10-R14 verified dataflow) ----------
  const int brow = (blk & 31) * 128;
  const int kcb = (blk >> 5) * KC_S;
  const int wid = t >> 6, lane = t & 63;
  const int wm = wid >> 1, wn = wid & 1;     // 4 x 2 waves
  const int lr = lane & 15, kh = lane >> 4;
  const int crow = t >> 2;                   // 0..127 (x-convert row)
  const int cj = t & 3;                      // x col group (16 f32 each)

  unsigned short* Ah = sm.sc.Ah;
  unsigned short* Al = sm.sc.Al;

  f32x4_t xr[2][4];
  f32x4_t acc[2][2] = {};

  auto stageW = [&](int buf, int k0) {
    int row = t >> 3, ch = t & 7;
    int sc = (ch ^ (row & 7)) * 8;           // pre-swizzled source (rule 21)
    gload16(Wrh + (size_t)row * D_DIM + k0 + sc, &sm.sc.Wh[buf][t * 8]);
    gload16(Wrl + (size_t)row * D_DIM + k0 + sc, &sm.sc.Wl[buf][t * 8]);
  };
  auto loadX = [&](int buf, int k0) {
    const float* p = x + (size_t)(brow + crow) * D_DIM + k0 + cj * 16;
    xr[buf][0] = *(const f32x4_t*)p;       xr[buf][1] = *(const f32x4_t*)(p + 4);
    xr[buf][2] = *(const f32x4_t*)(p + 8); xr[buf][3] = *(const f32x4_t*)(p + 12);
  };

  stageW(0, kcb);
  loadX(0, kcb);

#pragma unroll
  for (int s = 0; s < 4; ++s) {
    const int k0 = kcb + s * 64;
    if (s < 3) { stageW((s + 1) & 1, k0 + 64); loadX((s + 1) & 1, k0 + 64); }
#pragma unroll
    for (int u = 0; u < 2; ++u) {
      short8_t h, l;
      cvt_hilo8(xr[s & 1][u * 2], xr[s & 1][u * 2 + 1], h, l);
      int c = cj * 2 + u;
      int wch = (c ^ (crow & 7)) * 8;
      *(short8_t*)(Ah + crow * 64 + wch) = h;
      *(short8_t*)(Al + crow * 64 + wch) = l;
      *(short8_t*)(Xb + (size_t)(brow + crow) * D_DIM + k0 + c * 8) = h;
    }
    if (s < 3) { WAIT_VM(8); } else { WAIT_VM(2); }
    BARR();
    short8_t ah[2][2], al[2][2], bh[2][2], bl[2][2];
#pragma unroll
    for (int m = 0; m < 2; ++m)
#pragma unroll
      for (int ks = 0; ks < 2; ++ks) {
        int row = wm * 32 + m * 16 + lr;
        int ch = ((ks * 4 + kh) ^ (row & 7)) * 8;
        ah[m][ks] = *(const short8_t*)(Ah + row * 64 + ch);
        al[m][ks] = *(const short8_t*)(Al + row * 64 + ch);
      }
#pragma unroll
    for (int n = 0; n < 2; ++n)
#pragma unroll
      for (int ks = 0; ks < 2; ++ks) {
        int row = wn * 32 + n * 16 + lr;
        int ch = ((ks * 4 + kh) ^ (row & 7)) * 8;
        bh[n][ks] = *(const short8_t*)(&sm.sc.Wh[s & 1][row * 64 + ch]);
        bl[n][ks] = *(const short8_t*)(&sm.sc.Wl[s & 1][row * 64 + ch]);
      }
#pragma unroll
    for (int ks = 0; ks < 2; ++ks) {
#pragma unroll
      for (int m = 0; m < 2; ++m)
#pragma unroll
        for (int n = 0; n < 2; ++n)
          acc[m][n] = __builtin_amdgcn_mfma_f32_16x16x32_bf16(ah[m][ks], bh[n][ks], acc[m][n], 0, 0, 0);
#pragma unroll
      for (int m = 0; m < 2; ++m)
#pragma unroll
        for (int n = 0; n < 2; ++n)
          acc[m][n] = __builtin_amdgcn_mfma_f32_16x16x32_bf16(al[m][ks], bh[n][ks], acc[m][n], 0, 0, 0);
#pragma unroll
      for (int m = 0; m < 2; ++m)
#pragma unroll
        for (int n = 0; n < 2; ++n)
          acc[m][n] = __builtin_amdgcn_mfma_f32_16x16x32_bf16(ah[m][ks], bl[n][ks], acc[m][n], 0, 0, 0);
    }
    BARR();
  }

  // atomic accumulation into dense P (4096 x 64); order noise ~1e-6 << score gaps
#pragma unroll
  for (int m = 0; m < 2; ++m)
#pragma unroll
    for (int n = 0; n < 2; ++n)
#pragma unroll
      for (int j = 0; j < 4; ++j) {
        int row = brow + wm * 32 + m * 16 + kh * 4 + j;
        int e = wn * 32 + n * 16 + lr;
        atomicAdd(&P[(size_t)row * K_EXP + e], acc[m][n][j]);
      }
}

// ---------------- per-token top-16 + softmax -> dense G (N,64) ----------------
__global__ void topk_kernel(const float* __restrict__ P, float* __restrict__ G) {
  int wid = threadIdx.x >> 6, lane = threadIdx.x & 63;
  int n = blockIdx.x * 4 + wid;
  float rem = P[(size_t)n * K_EXP + lane];
  float topv[16]; int topi[16];
#pragma unroll
  for (int it = 0; it < 16; ++it) {
    float bv = rem; int bi = lane;
#pragma unroll
    for (int off = 32; off >= 1; off >>= 1) {
      float ov = __shfl_xor(bv, off);
      int oi = __shfl_xor(bi, off);
      if (ov > bv || (ov == bv && oi < bi)) { bv = ov; bi = oi; }
    }
    topv[it] = bv; topi[it] = bi;
    if (lane == bi) rem = -1e30f;
  }
  float mx = topv[0];
  float s = 0.f;
#pragma unroll
  for (int j = 0; j < 16; ++j) s += expf(topv[j] - mx);
  float g = 0.f;
#pragma unroll
  for (int j = 0; j < 16; ++j)
    if (topi[j] == lane) g = expf(topv[j] - mx) / s;
  G[(size_t)n * K_EXP + lane] = g;
}

// ---------------- 4-phase 256x256 MFMA GEMM (R13 frozen) ----------------
template <int KD, int EPI>   // EPI 0: bf16 partial out (stride KR); 1: f32*SCALE (stride D_DIM)
__global__ __launch_bounds__(512, 2)
void gemm8ph(const unsigned short* __restrict__ Aop,
             const unsigned short* __restrict__ Bop,
             void* __restrict__ Cout) {
  extern __shared__ unsigned short lds[];   // 2 x (A 256x64 + B 256x64) = 65536 shorts
  const int t = threadIdx.x;
  const int wid = t >> 6, lane = t & 63;
  const int wm = wid >> 2, wn = wid & 3;
  const int lr = lane & 15, kh = lane >> 4;

  int brow, bcol, kbeg;
  unsigned short* outb = nullptr;
  float* outf = nullptr;
  {
    int b = blockIdx.x;                    // 256 blocks, XCD-bijective remap
    int logical = (b & 7) * 32 + (b >> 3);
    if constexpr (EPI == 0) {
      int zb = logical >> 6;               // K split (4)
      int rem = logical & 63;
      brow = (rem >> 2) * 256;
      bcol = (rem & 3) * 256;
      kbeg = zb * KC_G;
      outb = (unsigned short*)Cout + (size_t)zb * N_TOK * KR;
    } else {
      brow = (logical >> 4) * 256;
      bcol = (logical & 15) * 256;
      kbeg = 0;
      outf = (float*)Cout;
    }
  }

  const int srow = t >> 3;                               // 0..63 within unit
  const int scoff = (((t & 7) ^ (srow & 7)) * 8);        // shorts
  const int ldoff = t * 8;                               // shorts
  const unsigned short* Abase = Aop + (size_t)(brow + srow) * KD + kbeg + scoff;
  const unsigned short* Bbase = Bop + (size_t)(bcol + srow) * KD + kbeg + scoff;

  auto stA = [&](int j, int T) {
    gload16(Abase + (size_t)j * 64 * KD + T * 64,
            lds + (T & 1) * 32768 + j * 4096 + ldoff);
  };
  auto stB = [&](int j, int T) {
    gload16(Bbase + (size_t)j * 64 * KD + T * 64,
            lds + (T & 1) * 32768 + 16384 + j * 4096 + ldoff);
  };
  auto rdA = [&](const unsigned short* LA, int m, int ks) -> short8_t {
    int r = wm * 128 + m * 16 + lr;
    int x = (ks * 32 + kh * 8) ^ ((lr & 7) << 3);
    return *(const short8_t*)(LA + r * 64 + x);
  };
  auto rdB = [&](const unsigned short* LB, int n, int ks) -> short8_t {
    int r = wn * 64 + n * 16 + lr;
    int x = (ks * 32 + kh * 8) ^ ((lr & 7) << 3);
    return *(const short8_t*)(LB + r * 64 + x);
  };

  f32x4_t acc[8][4] = {};
  short8_t bq[4][2], aq[2][2];

#define MFMA_QUAD(mb)                                                        \
  _Pragma("unroll")                                                          \
  for (int ks = 0; ks < 2; ++ks)                                             \
    _Pragma("unroll")                                                        \
    for (int mm = 0; mm < 2; ++mm)                                           \
      _Pragma("unroll")                                                      \
      for (int n = 0; n < 4; ++n)                                            \
        acc[(mb) + mm][n] = __builtin_amdgcn_mfma_f32_16x16x32_bf16(         \
            aq[mm][ks], bq[n][ks], acc[(mb) + mm][n], 0, 0, 0);

  stB(0, 0); stB(1, 0); stB(2, 0); stB(3, 0);
  stA(0, 0); stA(1, 0); stA(2, 0); stA(3, 0);
  stB(0, 1); stB(1, 1); stB(2, 1); stB(3, 1);
  stA(0, 1); stA(2, 1);
  WAIT_VM(6);
  BARR();

  for (int tt = 0; tt < 16; ++tt) {
    const unsigned short* LA = lds + (tt & 1) * 32768;
    const unsigned short* LB = LA + 16384;
#pragma unroll
    for (int n = 0; n < 4; ++n) { bq[n][0] = rdB(LB, n, 0); bq[n][1] = rdB(LB, n, 1); }
    aq[0][0] = rdA(LA, 0, 0); aq[0][1] = rdA(LA, 0, 1);
    aq[1][0] = rdA(LA, 1, 0); aq[1][1] = rdA(LA, 1, 1);
    if (tt + 1 < 16) { stA(1, tt + 1); stA(3, tt + 1); }
    BARR(); WAIT_LGKM0(); FENCE();
    __builtin_amdgcn_s_setprio(1);
    MFMA_QUAD(0)
    __builtin_amdgcn_s_setprio(0);
    BARR();
    aq[0][0] = rdA(LA, 2, 0); aq[0][1] = rdA(LA, 2, 1);
    aq[1][0] = rdA(LA, 3, 0); aq[1][1] = rdA(LA, 3, 1);
    if (tt + 2 < 16) { stB(0, tt + 2); stB(1, tt + 2); }
    WAIT_VM(10);
    BARR(); WAIT_LGKM0(); FENCE();
    __builtin_amdgcn_s_setprio(1);
    MFMA_QUAD(2)
    __builtin_amdgcn_s_setprio(0);
    BARR();
    aq[0][0] = rdA(LA, 4, 0); aq[0][1] = rdA(LA, 4, 1);
    aq[1][0] = rdA(LA, 5, 0); aq[1][1] = rdA(LA, 5, 1);
    if (tt + 2 < 16) { stB(2, tt + 2); stB(3, tt + 2); }
    BARR(); WAIT_LGKM0(); FENCE();
    __builtin_amdgcn_s_setprio(1);
    MFMA_QUAD(4)
    __builtin_amdgcn_s_setprio(0);
    BARR();
    aq[0][0] = rdA(LA, 6, 0); aq[0][1] = rdA(LA, 6, 1);
    aq[1][0] = rdA(LA, 7, 0); aq[1][1] = rdA(LA, 7, 1);
    if (tt + 2 < 16) { stA(0, tt + 2); stA(2, tt + 2); }
    WAIT_VM(8);
    BARR(); WAIT_LGKM0(); FENCE();
    __builtin_amdgcn_s_setprio(1);
    MFMA_QUAD(6)
    __builtin_amdgcn_s_setprio(0);
    BARR();
  }
#undef MFMA_QUAD

#pragma unroll
  for (int m = 0; m < 8; ++m) {
    int gr0 = brow + wm * 128 + m * 16 + kh * 4;
#pragma unroll
    for (int n = 0; n < 4; ++n) {
      int gc = bcol + wn * 64 + n * 16 + lr;
#pragma unroll
      for (int j = 0; j < 4; ++j) {
        if constexpr (EPI == 0)
          outb[(size_t)(gr0 + j) * KR + gc] = f2bf(acc[m][n][j]);
        else
          outf[(size_t)(gr0 + j) * D_DIM + gc] = acc[m][n][j] * SCALE_F;
      }
    }
  }
}

// ---------------- reduce split-K bf16 partials, apply gate, pack bf16 (vec8) -------
__global__ void reduce_gate_pack(const unsigned short* __restrict__ Pgb,
                                 const float* __restrict__ G,
                                 unsigned short* __restrict__ Hgb) {
  int idx = blockIdx.x * blockDim.x + threadIdx.x;   // N_TOK*KR/8 threads
  size_t i = (size_t)idx * 8;
  int n = (int)(i >> 10);
  int kr = (int)(i & 1023);
  float g = G[(size_t)n * K_EXP + (kr >> 4)];
  float s[8] = {};
#pragma unroll
  for (int z = 0; z < SPLIT_G; ++z) {
    short8_t v = *(const short8_t*)(Pgb + (size_t)z * N_TOK * KR + i);
#pragma unroll
    for (int j = 0; j < 8; ++j) s[j] += bf2f((unsigned short)v[j]);
  }
  short8_t o;
#pragma unroll
  for (int j = 0; j < 8; ++j) o[j] = (short)f2bf(s[j] * g);
  *(short8_t*)(Hgb + i) = o;
}

// ---------------- launch ----------------
extern "C" void kernel_launch(void* const* d_in, const int* in_sizes, int n_in,
                              void* d_out, int out_size, void* d_ws, size_t ws_size,
                              hipStream_t stream) {
  const float* x  = (const float*)d_in[0];   // (2,2048,4096)
  const float* A  = (const float*)d_in[1];   // (64,16,4096)
  const float* B  = (const float*)d_in[2];   // (64,4096,16)
  const float* Wr = (const float*)d_in[3];   // (64,4096)
  float* out = (float*)d_out;

  char* ws = (char*)d_ws;
  size_t off = 0;
  auto alloc = [&](size_t bytes) { void* p = ws + off; off += (bytes + 255) & ~255ull; return p; };
  float*          P   = (float*)alloc((size_t)N_TOK * K_EXP * 4);             // 1 MB
  float*          G   = (float*)alloc((size_t)N_TOK * K_EXP * 4);             // 1 MB
  unsigned short* Xb  = (unsigned short*)alloc((size_t)N_TOK * D_DIM * 2);    // 32 MB
  unsigned short* Ab  = (unsigned short*)alloc((size_t)KR * D_DIM * 2);       // 8 MB
  unsigned short* Wb  = (unsigned short*)alloc((size_t)D_DIM * KR * 2);       // 8 MB
  unsigned short* Hgb = (unsigned short*)alloc((size_t)N_TOK * KR * 2);       // 8 MB
  unsigned short* Pgb = (unsigned short*)alloc((size_t)SPLIT_G * N_TOK * KR * 2); // 32 MB
  unsigned short* Wrh = (unsigned short*)alloc((size_t)K_EXP * D_DIM * 2);    // 0.5 MB
  unsigned short* Wrl = (unsigned short*)alloc((size_t)K_EXP * D_DIM * 2);    // 0.5 MB
  (void)ws_size; (void)in_sizes; (void)n_in; (void)out_size;

  (void)hipFuncSetAttribute((const void*)&gemm8ph<D_DIM, 0>,
                            hipFuncAttributeMaxDynamicSharedMemorySize, 131072);
  (void)hipFuncSetAttribute((const void*)&gemm8ph<KR, 1>,
                            hipFuncAttributeMaxDynamicSharedMemorySize, 131072);

  // P accumulates atomically each call -> zero it every launch (graph-replayed)
  hipMemsetAsync(P, 0, (size_t)N_TOK * K_EXP * 4, stream);

  pack_wr<<<K_EXP * D_DIM / 4 / 512, 512, 0, stream>>>(Wr, Wrh, Wrl);

  // fused front-end: scores (512 blocks) | pack A (512) | pack B transpose (128)
  fused_front<<<1152, 512, 0, stream>>>(x, Wrh, Wrl, P, Xb, A, Ab, B, Wb);

  topk_kernel<<<N_TOK / 4, 256, 0, stream>>>(P, G);

  // GEMM1: Pgb[z] = bf16(Xb @ Ab^T) over K-chunk z  (256 blocks: 16M x 4N x 4z)
  gemm8ph<D_DIM, 0><<<256, 512, 131072, stream>>>(Xb, Ab, Pgb);
  reduce_gate_pack<<<N_TOK * KR / 8 / 256, 256, 0, stream>>>(Pgb, G, Hgb);

  // GEMM2: out = SCALE * Hgb @ Wb^T  (256 blocks: 16M x 16N)
  gemm8ph<KR, 1><<<256, 512, 131072, stream>>>(Hgb, Wb, out);
}

// Round 16
// 132.644 us; speedup vs baseline: 1.0379x; 1.0379x over previous
//
#include <hip/hip_runtime.h>
#include <hip/hip_bf16.h>

#define D_DIM 4096
#define N_TOK 4096
#define K_EXP 64
#define R_RANK 16
#define KR 1024               // K_EXP * R_RANK
#define SCALE_F 2.0f          // ALPHA / RANK
#define SPLIT_S 16
#define KC_S (D_DIM / SPLIT_S)   // 256
#define SPLIT_G 4
#define KC_G (D_DIM / SPLIT_G)   // 1024

typedef __attribute__((ext_vector_type(8))) short short8_t;   // 8 x bf16
typedef __attribute__((ext_vector_type(4))) float f32x4_t;
typedef __attribute__((ext_vector_type(4))) unsigned short u16x4_t;

__device__ __forceinline__ unsigned short f2bf(float f) {
  unsigned int u = __builtin_bit_cast(unsigned int, f);
  u += 0x7fffu + ((u >> 16) & 1u);          // RTNE
  return (unsigned short)(u >> 16);
}
__device__ __forceinline__ float bf2f(unsigned short h) {
  return __builtin_bit_cast(float, ((unsigned int)h) << 16);
}

// hi/lo split of 8 f32 -> bf16 hi + bf16 lo
__device__ __forceinline__ void cvt_hilo8(const f32x4_t a, const f32x4_t b,
                                          short8_t& h, short8_t& l) {
#pragma unroll
  for (int j = 0; j < 8; ++j) {
    float f = (j < 4) ? a[j & 3] : b[j & 3];
    __hip_bfloat16 hb = __float2bfloat16(f);
    float hf = __bfloat162float(hb);
    __hip_bfloat16 lb = __float2bfloat16(f - hf);
    h[j] = (short)__builtin_bit_cast(unsigned short, hb);
    l[j] = (short)__builtin_bit_cast(unsigned short, lb);
  }
}

// async global->LDS, 16B per lane. LDS dest must be wave-uniform base + lane*16.
__device__ __forceinline__ void gload16(const void* g, void* l) {
  __builtin_amdgcn_global_load_lds(
      (const __attribute__((address_space(1))) unsigned int*)g,
      (__attribute__((address_space(3))) unsigned int*)l, 16, 0, 0);
}

#define BARR() __builtin_amdgcn_s_barrier()
#define FENCE() __builtin_amdgcn_sched_barrier(0)
#define WAIT_LGKM0() asm volatile("s_waitcnt lgkmcnt(0)" ::: "memory")
#define WAIT_VM(n) asm volatile("s_waitcnt vmcnt(" #n ")" ::: "memory")

// ---------------- merged pack kernel (A cast, B transpose-cast, Wr hi/lo) ---------
__global__ void pack_all(const float* __restrict__ A, unsigned short* __restrict__ Ab,
                         const float* __restrict__ B, unsigned short* __restrict__ Wb,
                         const float* __restrict__ Wr,
                         unsigned short* __restrict__ Wrh, unsigned short* __restrict__ Wrl) {
  int b = blockIdx.x;
  if (b < 1024) {
    int n4 = KR * D_DIM / 4;
    for (int i = b * 256 + threadIdx.x; i < n4; i += 1024 * 256) {
      f32x4_t v = *(const f32x4_t*)(A + (size_t)i * 4);
      u16x4_t o;
      o[0] = f2bf(v[0]); o[1] = f2bf(v[1]); o[2] = f2bf(v[2]); o[3] = f2bf(v[3]);
      *(u16x4_t*)(Ab + (size_t)i * 4) = o;
    }
  } else if (b < 2048) {
    int n = K_EXP * D_DIM * 4;
    for (int i = (b - 1024) * 256 + threadIdx.x; i < n; i += 1024 * 256) {
      int k   = i >> 14;
      int rem = i & 16383;
      int d   = rem >> 2;
      int r4  = (rem & 3) * 4;
      f32x4_t v = *(const f32x4_t*)(B + ((size_t)(k * D_DIM + d) * R_RANK + r4));
      u16x4_t o;
      o[0] = f2bf(v[0]); o[1] = f2bf(v[1]); o[2] = f2bf(v[2]); o[3] = f2bf(v[3]);
      *(u16x4_t*)(Wb + ((size_t)d * KR + k * R_RANK + r4)) = o;
    }
  } else {
    int i = (b - 2048) * 256 + threadIdx.x;          // 65536 quads
    f32x4_t v = *(const f32x4_t*)(Wr + (size_t)i * 4);
    u16x4_t h, l;
#pragma unroll
    for (int j = 0; j < 4; ++j) {
      __hip_bfloat16 hb = __float2bfloat16(v[j]);
      float hf = __bfloat162float(hb);
      __hip_bfloat16 lb = __float2bfloat16(v[j] - hf);
      h[j] = __builtin_bit_cast(unsigned short, hb);
      l[j] = __builtin_bit_cast(unsigned short, lb);
    }
    *(u16x4_t*)(Wrh + (size_t)i * 4) = h;
    *(u16x4_t*)(Wrl + (size_t)i * 4) = l;
  }
}

// ---------------- router scores v6 + MFMA chain-spacing reorder ----------------
__global__ __launch_bounds__(512, 4)
void scores_mfma(const float* __restrict__ x,
                 const unsigned short* __restrict__ Wrh,
                 const unsigned short* __restrict__ Wrl,
                 float* __restrict__ P, unsigned short* __restrict__ Xb) {
  __shared__ unsigned short Ah[128 * 64];    // 16 KB, XOR-swizzled
  __shared__ unsigned short Al[128 * 64];    // 16 KB
  __shared__ unsigned short Wh[2][64 * 64];  // 2 x 8 KB (dbuf)
  __shared__ unsigned short Wl[2][64 * 64];  // 2 x 8 KB
  const int t = threadIdx.x;
  const int brow = blockIdx.x * 128;
  const int kcb = blockIdx.y * KC_S;
  const int wid = t >> 6, lane = t & 63;
  const int wm = wid >> 1, wn = wid & 1;     // 4 x 2 waves
  const int lr = lane & 15, kh = lane >> 4;
  const int crow = t >> 2;                   // 0..127 (x-convert row)
  const int cj = t & 3;                      // x col group (16 f32 each)

  f32x4_t xr[2][4];
  f32x4_t acc[2][2] = {};

  auto stageW = [&](int buf, int k0) {
    int row = t >> 3, ch = t & 7;
    int sc = (ch ^ (row & 7)) * 8;           // pre-swizzled source (rule 21)
    gload16(Wrh + (size_t)row * D_DIM + k0 + sc, &Wh[buf][t * 8]);
    gload16(Wrl + (size_t)row * D_DIM + k0 + sc, &Wl[buf][t * 8]);
  };
  auto loadX = [&](int buf, int k0) {
    const float* p = x + (size_t)(brow + crow) * D_DIM + k0 + cj * 16;
    xr[buf][0] = *(const f32x4_t*)p;       xr[buf][1] = *(const f32x4_t*)(p + 4);
    xr[buf][2] = *(const f32x4_t*)(p + 8); xr[buf][3] = *(const f32x4_t*)(p + 12);
  };

  stageW(0, kcb);
  loadX(0, kcb);

#pragma unroll
  for (int s = 0; s < 4; ++s) {
    const int k0 = kcb + s * 64;
    if (s < 3) { stageW((s + 1) & 1, k0 + 64); loadX((s + 1) & 1, k0 + 64); }
#pragma unroll
    for (int u = 0; u < 2; ++u) {
      short8_t h, l;
      cvt_hilo8(xr[s & 1][u * 2], xr[s & 1][u * 2 + 1], h, l);
      int c = cj * 2 + u;
      int wch = (c ^ (crow & 7)) * 8;
      *(short8_t*)(Ah + crow * 64 + wch) = h;
      *(short8_t*)(Al + crow * 64 + wch) = l;
      *(short8_t*)(Xb + (size_t)(brow + crow) * D_DIM + k0 + c * 8) = h;
    }
    if (s < 3) { WAIT_VM(8); } else { WAIT_VM(2); }
    BARR();
    short8_t ah[2][2], al[2][2], bh[2][2], bl[2][2];
#pragma unroll
    for (int m = 0; m < 2; ++m)
#pragma unroll
      for (int ks = 0; ks < 2; ++ks) {
        int row = wm * 32 + m * 16 + lr;
        int ch = ((ks * 4 + kh) ^ (row & 7)) * 8;
        ah[m][ks] = *(const short8_t*)(Ah + row * 64 + ch);
        al[m][ks] = *(const short8_t*)(Al + row * 64 + ch);
      }
#pragma unroll
    for (int n = 0; n < 2; ++n)
#pragma unroll
      for (int ks = 0; ks < 2; ++ks) {
        int row = wn * 32 + n * 16 + lr;
        int ch = ((ks * 4 + kh) ^ (row & 7)) * 8;
        bh[n][ks] = *(const short8_t*)(&Wh[s & 1][row * 64 + ch]);
        bl[n][ks] = *(const short8_t*)(&Wl[s & 1][row * 64 + ch]);
      }
    // chain-spaced: (ks, variant) outer, (m,n) inner -> 4 indep ops between
    // consecutive uses of the same acc[m][n]
#pragma unroll
    for (int ks = 0; ks < 2; ++ks) {
#pragma unroll
      for (int m = 0; m < 2; ++m)
#pragma unroll
        for (int n = 0; n < 2; ++n)
          acc[m][n] = __builtin_amdgcn_mfma_f32_16x16x32_bf16(ah[m][ks], bh[n][ks], acc[m][n], 0, 0, 0);
#pragma unroll
      for (int m = 0; m < 2; ++m)
#pragma unroll
        for (int n = 0; n < 2; ++n)
          acc[m][n] = __builtin_amdgcn_mfma_f32_16x16x32_bf16(al[m][ks], bh[n][ks], acc[m][n], 0, 0, 0);
#pragma unroll
      for (int m = 0; m < 2; ++m)
#pragma unroll
        for (int n = 0; n < 2; ++n)
          acc[m][n] = __builtin_amdgcn_mfma_f32_16x16x32_bf16(ah[m][ks], bl[n][ks], acc[m][n], 0, 0, 0);
    }
    BARR();
  }

  float* Pb = P + (size_t)blockIdx.y * N_TOK * K_EXP;
#pragma unroll
  for (int m = 0; m < 2; ++m)
#pragma unroll
    for (int n = 0; n < 2; ++n)
#pragma unroll
      for (int j = 0; j < 4; ++j) {
        int row = brow + wm * 32 + m * 16 + kh * 4 + j;
        int e = wn * 32 + n * 16 + lr;
        Pb[(size_t)row * K_EXP + e] = acc[m][n][j];
      }
}

// ---------------- per-token top-16 + softmax -> dense G (N,64) ----------------
__global__ void topk_kernel(const float* __restrict__ P, float* __restrict__ G) {
  int wid = threadIdx.x >> 6, lane = threadIdx.x & 63;
  int n = blockIdx.x * 4 + wid;
  float rem = 0.f;
#pragma unroll
  for (int c = 0; c < SPLIT_S; ++c)
    rem += P[((size_t)c * N_TOK + n) * K_EXP + lane];
  float topv[16]; int topi[16];
#pragma unroll
  for (int it = 0; it < 16; ++it) {
    float bv = rem; int bi = lane;
#pragma unroll
    for (int off = 32; off >= 1; off >>= 1) {
      float ov = __shfl_xor(bv, off);
      int oi = __shfl_xor(bi, off);
      if (ov > bv || (ov == bv && oi < bi)) { bv = ov; bi = oi; }
    }
    topv[it] = bv; topi[it] = bi;
    if (lane == bi) rem = -1e30f;
  }
  float mx = topv[0];
  float s = 0.f;
#pragma unroll
  for (int j = 0; j < 16; ++j) s += expf(topv[j] - mx);
  float g = 0.f;
#pragma unroll
  for (int j = 0; j < 16; ++j)
    if (topi[j] == lane) g = expf(topv[j] - mx) / s;
  G[(size_t)n * K_EXP + lane] = g;
}

// ---------------- 4-phase 256x256 MFMA GEMM (R10 schedule, ks-outer MFMA) ---------
// 512 thr = 8 waves (2M x 4N), BK=64, 16 K-tiles, 2 LDS buffers (128 KiB).
template <int KD, int EPI>   // EPI 0: bf16 partial out (stride KR); 1: f32*SCALE (stride D_DIM)
__global__ __launch_bounds__(512, 2)
void gemm8ph(const unsigned short* __restrict__ Aop,
             const unsigned short* __restrict__ Bop,
             void* __restrict__ Cout) {
  extern __shared__ unsigned short lds[];   // 2 x (A 256x64 + B 256x64) = 65536 shorts
  const int t = threadIdx.x;
  const int wid = t >> 6, lane = t & 63;
  const int wm = wid >> 2, wn = wid & 3;
  const int lr = lane & 15, kh = lane >> 4;

  int brow, bcol, kbeg;
  unsigned short* outb = nullptr;
  float* outf = nullptr;
  {
    int b = blockIdx.x;                    // 256 blocks, XCD-bijective remap
    int logical = (b & 7) * 32 + (b >> 3);
    if constexpr (EPI == 0) {
      int zb = logical >> 6;               // K split (4)
      int rem = logical & 63;
      brow = (rem >> 2) * 256;
      bcol = (rem & 3) * 256;
      kbeg = zb * KC_G;
      outb = (unsigned short*)Cout + (size_t)zb * N_TOK * KR;
    } else {
      brow = (logical >> 4) * 256;
      bcol = (logical & 15) * 256;
      kbeg = 0;
      outf = (float*)Cout;
    }
  }

  const int srow = t >> 3;                               // 0..63 within unit
  const int scoff = (((t & 7) ^ (srow & 7)) * 8);        // shorts
  const int ldoff = t * 8;                               // shorts
  const unsigned short* Abase = Aop + (size_t)(brow + srow) * KD + kbeg + scoff;
  const unsigned short* Bbase = Bop + (size_t)(bcol + srow) * KD + kbeg + scoff;

  auto stA = [&](int j, int T) {
    gload16(Abase + (size_t)j * 64 * KD + T * 64,
            lds + (T & 1) * 32768 + j * 4096 + ldoff);
  };
  auto stB = [&](int j, int T) {
    gload16(Bbase + (size_t)j * 64 * KD + T * 64,
            lds + (T & 1) * 32768 + 16384 + j * 4096 + ldoff);
  };
  auto rdA = [&](const unsigned short* LA, int m, int ks) -> short8_t {
    int r = wm * 128 + m * 16 + lr;
    int x = (ks * 32 + kh * 8) ^ ((lr & 7) << 3);
    return *(const short8_t*)(LA + r * 64 + x);
  };
  auto rdB = [&](const unsigned short* LB, int n, int ks) -> short8_t {
    int r = wn * 64 + n * 16 + lr;
    int x = (ks * 32 + kh * 8) ^ ((lr & 7) << 3);
    return *(const short8_t*)(LB + r * 64 + x);
  };

  f32x4_t acc[8][4] = {};
  short8_t bq[4][2], aq[2][2];

  // ks-outer: 8 independent MFMAs between dependent uses of the same acc
#define MFMA_QUAD(mb)                                                        \
  _Pragma("unroll")                                                          \
  for (int ks = 0; ks < 2; ++ks)                                             \
    _Pragma("unroll")                                                        \
    for (int mm = 0; mm < 2; ++mm)                                           \
      _Pragma("unroll")                                                      \
      for (int n = 0; n < 4; ++n)                                            \
        acc[(mb) + mm][n] = __builtin_amdgcn_mfma_f32_16x16x32_bf16(         \
            aq[mm][ks], bq[n][ks], acc[(mb) + mm][n], 0, 0, 0);

  // ---- prologue: tile0 full (8 units), tile1 B*,A0,A2 (6 units) = 14 loads
  stB(0, 0); stB(1, 0); stB(2, 0); stB(3, 0);
  stA(0, 0); stA(1, 0); stA(2, 0); stA(3, 0);
  stB(0, 1); stB(1, 1); stB(2, 1); stB(3, 1);
  stA(0, 1); stA(2, 1);
  WAIT_VM(6);
  BARR();

  for (int tt = 0; tt < 16; ++tt) {
    const unsigned short* LA = lds + (tt & 1) * 32768;
    const unsigned short* LB = LA + 16384;
    // ---------- phase 0: all B frags + A m0,1 ----------
#pragma unroll
    for (int n = 0; n < 4; ++n) { bq[n][0] = rdB(LB, n, 0); bq[n][1] = rdB(LB, n, 1); }
    aq[0][0] = rdA(LA, 0, 0); aq[0][1] = rdA(LA, 0, 1);
    aq[1][0] = rdA(LA, 1, 0); aq[1][1] = rdA(LA, 1, 1);
    if (tt + 1 < 16) { stA(1, tt + 1); stA(3, tt + 1); }
    BARR(); WAIT_LGKM0(); FENCE();
    __builtin_amdgcn_s_setprio(1);
    MFMA_QUAD(0)
    __builtin_amdgcn_s_setprio(0);
    BARR();
    // ---------- phase 1: A m2,3 ----------
    aq[0][0] = rdA(LA, 2, 0); aq[0][1] = rdA(LA, 2, 1);
    aq[1][0] = rdA(LA, 3, 0); aq[1][1] = rdA(LA, 3, 1);
    if (tt + 2 < 16) { stB(0, tt + 2); stB(1, tt + 2); }
    WAIT_VM(10);
    BARR(); WAIT_LGKM0(); FENCE();
    __builtin_amdgcn_s_setprio(1);
    MFMA_QUAD(2)
    __builtin_amdgcn_s_setprio(0);
    BARR();
    // ---------- phase 2: A m4,5 ----------
    aq[0][0] = rdA(LA, 4, 0); aq[0][1] = rdA(LA, 4, 1);
    aq[1][0] = rdA(LA, 5, 0); aq[1][1] = rdA(LA, 5, 1);
    if (tt + 2 < 16) { stB(2, tt + 2); stB(3, tt + 2); }
    BARR(); WAIT_LGKM0(); FENCE();
    __builtin_amdgcn_s_setprio(1);
    MFMA_QUAD(4)
    __builtin_amdgcn_s_setprio(0);
    BARR();
    // ---------- phase 3: A m6,7 ----------
    aq[0][0] = rdA(LA, 6, 0); aq[0][1] = rdA(LA, 6, 1);
    aq[1][0] = rdA(LA, 7, 0); aq[1][1] = rdA(LA, 7, 1);
    if (tt + 2 < 16) { stA(0, tt + 2); stA(2, tt + 2); }
    WAIT_VM(8);
    BARR(); WAIT_LGKM0(); FENCE();
    __builtin_amdgcn_s_setprio(1);
    MFMA_QUAD(6)
    __builtin_amdgcn_s_setprio(0);
    BARR();
  }
#undef MFMA_QUAD

  // ---- epilogue ----
#pragma unroll
  for (int m = 0; m < 8; ++m) {
    int gr0 = brow + wm * 128 + m * 16 + kh * 4;
#pragma unroll
    for (int n = 0; n < 4; ++n) {
      int gc = bcol + wn * 64 + n * 16 + lr;
#pragma unroll
      for (int j = 0; j < 4; ++j) {
        if constexpr (EPI == 0)
          outb[(size_t)(gr0 + j) * KR + gc] = f2bf(acc[m][n][j]);
        else
          outf[(size_t)(gr0 + j) * D_DIM + gc] = acc[m][n][j] * SCALE_F;
      }
    }
  }
}

// ---------------- reduce split-K bf16 partials, apply gate, pack bf16 (vec8) -------
__global__ void reduce_gate_pack(const unsigned short* __restrict__ Pgb,
                                 const float* __restrict__ G,
                                 unsigned short* __restrict__ Hgb) {
  int idx = blockIdx.x * blockDim.x + threadIdx.x;   // N_TOK*KR/8 threads
  size_t i = (size_t)idx * 8;
  int n = (int)(i >> 10);
  int kr = (int)(i & 1023);
  float g = G[(size_t)n * K_EXP + (kr >> 4)];
  float s[8] = {};
#pragma unroll
  for (int z = 0; z < SPLIT_G; ++z) {
    short8_t v = *(const short8_t*)(Pgb + (size_t)z * N_TOK * KR + i);
#pragma unroll
    for (int j = 0; j < 8; ++j) s[j] += bf2f((unsigned short)v[j]);
  }
  short8_t o;
#pragma unroll
  for (int j = 0; j < 8; ++j) o[j] = (short)f2bf(s[j] * g);
  *(short8_t*)(Hgb + i) = o;
}

// ---------------- launch ----------------
extern "C" void kernel_launch(void* const* d_in, const int* in_sizes, int n_in,
                              void* d_out, int out_size, void* d_ws, size_t ws_size,
                              hipStream_t stream) {
  const float* x  = (const float*)d_in[0];   // (2,2048,4096)
  const float* A  = (const float*)d_in[1];   // (64,16,4096)
  const float* B  = (const float*)d_in[2];   // (64,4096,16)
  const float* Wr = (const float*)d_in[3];   // (64,4096)
  float* out = (float*)d_out;

  char* ws = (char*)d_ws;
  size_t off = 0;
  auto alloc = [&](size_t bytes) { void* p = ws + off; off += (bytes + 255) & ~255ull; return p; };
  float*          P   = (float*)alloc((size_t)SPLIT_S * N_TOK * K_EXP * 4);   // 16 MB
  float*          G   = (float*)alloc((size_t)N_TOK * K_EXP * 4);             // 1 MB
  unsigned short* Xb  = (unsigned short*)alloc((size_t)N_TOK * D_DIM * 2);    // 32 MB
  unsigned short* Ab  = (unsigned short*)alloc((size_t)KR * D_DIM * 2);       // 8 MB
  unsigned short* Wb  = (unsigned short*)alloc((size_t)D_DIM * KR * 2);       // 8 MB
  unsigned short* Hgb = (unsigned short*)alloc((size_t)N_TOK * KR * 2);       // 8 MB
  unsigned short* Pgb = (unsigned short*)alloc((size_t)SPLIT_G * N_TOK * KR * 2); // 32 MB
  unsigned short* Wrh = (unsigned short*)alloc((size_t)K_EXP * D_DIM * 2);    // 0.5 MB
  unsigned short* Wrl = (unsigned short*)alloc((size_t)K_EXP * D_DIM * 2);    // 0.5 MB
  (void)ws_size; (void)in_sizes; (void)n_in; (void)out_size;

  (void)hipFuncSetAttribute((const void*)&gemm8ph<D_DIM, 0>,
                            hipFuncAttributeMaxDynamicSharedMemorySize, 131072);
  (void)hipFuncSetAttribute((const void*)&gemm8ph<KR, 1>,
                            hipFuncAttributeMaxDynamicSharedMemorySize, 131072);

  pack_all<<<2304, 256, 0, stream>>>(A, Ab, B, Wb, Wr, Wrh, Wrl);

  scores_mfma<<<dim3(N_TOK / 128, SPLIT_S), 512, 0, stream>>>(x, Wrh, Wrl, P, Xb);
  topk_kernel<<<N_TOK / 4, 256, 0, stream>>>(P, G);

  // GEMM1: Pgb[z] = bf16(Xb @ Ab^T) over K-chunk z  (256 blocks: 16M x 4N x 4z)
  gemm8ph<D_DIM, 0><<<256, 512, 131072, stream>>>(Xb, Ab, Pgb);
  reduce_gate_pack<<<N_TOK * KR / 8 / 256, 256, 0, stream>>>(Pgb, G, Hgb);

  // GEMM2: out = SCALE * Hgb @ Wb^T  (256 blocks: 16M x 16N)
  gemm8ph<KR, 1><<<256, 512, 131072, stream>>>(Hgb, Wb, out);
}